// Round 2
// baseline (553.590 us; speedup 1.0000x reference)
//
#include <hip/hip_runtime.h>
#include <hip/hip_bf16.h>

#define D 128
#define LDK 136  // padded LDS row: 136 bf16 = 272B (16B-aligned rows, breaks 32-way bank conflict)

typedef __bf16 bf16x8 __attribute__((ext_vector_type(8)));
typedef float  f32x4  __attribute__((ext_vector_type(4)));
typedef unsigned short u16;

// fp32 -> bf16 round-to-nearest-even
__device__ __forceinline__ u16 f2bf(float f) {
    unsigned int u = __builtin_bit_cast(unsigned int, f);
    u = u + 0x7FFFu + ((u >> 16) & 1u);
    return (u16)(u >> 16);
}
__device__ __forceinline__ unsigned int pk2(float lo, float hi) {
    return (unsigned int)f2bf(lo) | ((unsigned int)f2bf(hi) << 16);
}
// convert 8 fp32 -> 8 bf16, one 16B LDS store (dst 16B aligned)
__device__ __forceinline__ void cvt_store8(u16* dst, float4 a, float4 b) {
    uint4 v;
    v.x = pk2(a.x, a.y); v.y = pk2(a.z, a.w);
    v.z = pk2(b.x, b.y); v.w = pk2(b.z, b.w);
    *reinterpret_cast<uint4*>(dst) = v;
}

// ---------------- edge kernel: msg = relu(x[src] + ea@We^T + be); atomic scatter to aggr[dst]
__global__ __launch_bounds__(256, 2)
void gine_edge(const float* __restrict__ x,
               const int* __restrict__ ei,      // int32 (harness converts integer inputs)
               const float* __restrict__ ea,
               const float* __restrict__ We,
               const float* __restrict__ be,
               float* __restrict__ aggr,
               int E)
{
    __shared__ u16 a_lds[128][LDK];   // edge_attr tile (bf16)
    __shared__ u16 w_lds[128][LDK];   // We[o][k] (bf16)
    __shared__ int sd_lds[2][128];    // src, dst

    const int tid = threadIdx.x;
    const int e0  = blockIdx.x * 128;

    {   // stage: thread t -> tile row t>>1, 64-col half (t&1)
        const int row = tid >> 1;
        const int c0  = (tid & 1) * 64;
        int erow = e0 + row; if (erow >= E) erow = E - 1;
        const float4* ga = reinterpret_cast<const float4*>(ea + (size_t)erow * D + c0);
        const float4* gw = reinterpret_cast<const float4*>(We + (size_t)row  * D + c0);
        #pragma unroll
        for (int j = 0; j < 8; ++j) {
            float4 u0 = ga[2*j], u1 = ga[2*j+1];
            cvt_store8(&a_lds[row][c0 + 8*j], u0, u1);
            float4 w0 = gw[2*j], w1 = gw[2*j+1];
            cvt_store8(&w_lds[row][c0 + 8*j], w0, w1);
        }
    }
    {   // stage src/dst (int32)
        const int r = tid & 127, which = tid >> 7;
        int erow = e0 + r;
        sd_lds[which][r] = (erow < E) ? ei[(size_t)which * E + erow] : 0;
    }
    __syncthreads();

    const int wave = tid >> 6, lane = tid & 63;
    const int lhi = lane >> 4, llo = lane & 15;
    const int r0 = wave * 32;   // wave owns 32 tile rows x 128 cols

    f32x4 acc[2][8];
    #pragma unroll
    for (int m = 0; m < 2; ++m)
        #pragma unroll
        for (int n = 0; n < 8; ++n) acc[m][n] = (f32x4){0.f, 0.f, 0.f, 0.f};

    #pragma unroll
    for (int kk = 0; kk < 4; ++kk) {
        const int k0 = kk * 32 + lhi * 8;
        bf16x8 a0 = *reinterpret_cast<const bf16x8*>(&a_lds[r0 + llo][k0]);
        bf16x8 a1 = *reinterpret_cast<const bf16x8*>(&a_lds[r0 + 16 + llo][k0]);
        #pragma unroll
        for (int nf = 0; nf < 8; ++nf) {
            bf16x8 b = *reinterpret_cast<const bf16x8*>(&w_lds[nf*16 + llo][k0]);
            acc[0][nf] = __builtin_amdgcn_mfma_f32_16x16x32_bf16(a0, b, acc[0][nf], 0, 0, 0);
            acc[1][nf] = __builtin_amdgcn_mfma_f32_16x16x32_bf16(a1, b, acc[1][nf], 0, 0, 0);
        }
    }

    float bev[8];
    #pragma unroll
    for (int nf = 0; nf < 8; ++nf) bev[nf] = be[nf*16 + llo];

    // epilogue: C/D frag (col = lane&15, row = (lane>>4)*4 + reg)
    #pragma unroll
    for (int mf = 0; mf < 2; ++mf) {
        #pragma unroll
        for (int r = 0; r < 4; ++r) {
            const int row = r0 + mf*16 + lhi*4 + r;
            if (e0 + row >= E) continue;
            const int s = sd_lds[0][row];
            const int d = sd_lds[1][row];
            const float* xr  = x    + (size_t)s * D;
            float*      arow = aggr + (size_t)d * D;
            #pragma unroll
            for (int nf = 0; nf < 8; ++nf) {
                const int col = nf*16 + llo;
                float v = acc[mf][nf][r] + xr[col] + bev[nf];
                v = fmaxf(v, 0.0f);
                atomicAdd(&arow[col], v);
            }
        }
    }
}

// ---------------- node kernel: h0=(1+eps)x+aggr; GEMM1+BN+ReLU; GEMM2+b2; LN; relu(+x)
__global__ __launch_bounds__(256, 2)
void gine_node(const float* __restrict__ x,
               const float* __restrict__ aggr,
               const float* __restrict__ epsp,
               const float* __restrict__ W1,
               const float* __restrict__ b1,
               const float* __restrict__ bn_g,
               const float* __restrict__ bn_b,
               const float* __restrict__ bn_rm,
               const float* __restrict__ bn_rv,
               const float* __restrict__ W2,
               const float* __restrict__ b2,
               const float* __restrict__ ln_g,
               const float* __restrict__ ln_b,
               float* __restrict__ out,
               int N)
{
    __shared__ u16 h_lds[128][LDK];   // A operand: h0 then h1
    __shared__ u16 w_lds[128][LDK];   // B operand: W1 then W2

    const int tid = threadIdx.x;
    const int n0  = blockIdx.x * 128;
    const float epf = 1.0f + epsp[0];

    {   // stage h0 = (1+eps)*x + aggr, and W1
        const int row = tid >> 1;
        const int c0  = (tid & 1) * 64;
        int nrow = n0 + row; if (nrow >= N) nrow = N - 1;
        const float4* gx = reinterpret_cast<const float4*>(x    + (size_t)nrow * D + c0);
        const float4* ga = reinterpret_cast<const float4*>(aggr + (size_t)nrow * D + c0);
        const float4* gw = reinterpret_cast<const float4*>(W1   + (size_t)row  * D + c0);
        #pragma unroll
        for (int j = 0; j < 8; ++j) {
            float4 xv0 = gx[2*j], xv1 = gx[2*j+1];
            float4 av0 = ga[2*j], av1 = ga[2*j+1];
            float4 h0, h1;
            h0.x = epf*xv0.x + av0.x; h0.y = epf*xv0.y + av0.y;
            h0.z = epf*xv0.z + av0.z; h0.w = epf*xv0.w + av0.w;
            h1.x = epf*xv1.x + av1.x; h1.y = epf*xv1.y + av1.y;
            h1.z = epf*xv1.z + av1.z; h1.w = epf*xv1.w + av1.w;
            cvt_store8(&h_lds[row][c0 + 8*j], h0, h1);
            float4 w0 = gw[2*j], w1 = gw[2*j+1];
            cvt_store8(&w_lds[row][c0 + 8*j], w0, w1);
        }
    }
    __syncthreads();

    const int wave = tid >> 6, lane = tid & 63;
    const int lhi = lane >> 4, llo = lane & 15;
    const int r0 = wave * 32;

    f32x4 acc[2][8];
    #pragma unroll
    for (int m = 0; m < 2; ++m)
        #pragma unroll
        for (int n = 0; n < 8; ++n) acc[m][n] = (f32x4){0.f, 0.f, 0.f, 0.f};

    #pragma unroll
    for (int kk = 0; kk < 4; ++kk) {
        const int k0 = kk * 32 + lhi * 8;
        bf16x8 a0 = *reinterpret_cast<const bf16x8*>(&h_lds[r0 + llo][k0]);
        bf16x8 a1 = *reinterpret_cast<const bf16x8*>(&h_lds[r0 + 16 + llo][k0]);
        #pragma unroll
        for (int nf = 0; nf < 8; ++nf) {
            bf16x8 b = *reinterpret_cast<const bf16x8*>(&w_lds[nf*16 + llo][k0]);
            acc[0][nf] = __builtin_amdgcn_mfma_f32_16x16x32_bf16(a0, b, acc[0][nf], 0, 0, 0);
            acc[1][nf] = __builtin_amdgcn_mfma_f32_16x16x32_bf16(a1, b, acc[1][nf], 0, 0, 0);
        }
    }

    // per-lane per-column constants (col = nf*16 + llo)
    float sc[8], bi[8], b2v[8], lgv[8], lbv[8];
    #pragma unroll
    for (int nf = 0; nf < 8; ++nf) {
        const int c = nf*16 + llo;
        const float s = bn_g[c] * rsqrtf(bn_rv[c] + 1e-5f);
        sc[nf]  = s;
        bi[nf]  = (b1[c] - bn_rm[c]) * s + bn_b[c];   // BN folded with b1
        b2v[nf] = b2[c];
        lgv[nf] = ln_g[c];
        lbv[nf] = ln_b[c];
    }

    __syncthreads();   // all GEMM1 LDS reads complete before overwrite

    // h1 = relu(BN(GEMM1)) -> h_lds (bf16, scattered u16 stores); stage W2
    #pragma unroll
    for (int mf = 0; mf < 2; ++mf) {
        #pragma unroll
        for (int r = 0; r < 4; ++r) {
            const int row = r0 + mf*16 + lhi*4 + r;
            #pragma unroll
            for (int nf = 0; nf < 8; ++nf) {
                const int col = nf*16 + llo;
                const float v = fmaxf(acc[mf][nf][r] * sc[nf] + bi[nf], 0.0f);
                h_lds[row][col] = f2bf(v);
            }
        }
    }
    {
        const int row = tid >> 1;
        const int c0  = (tid & 1) * 64;
        const float4* gw = reinterpret_cast<const float4*>(W2 + (size_t)row * D + c0);
        #pragma unroll
        for (int j = 0; j < 8; ++j) {
            float4 w0 = gw[2*j], w1 = gw[2*j+1];
            cvt_store8(&w_lds[row][c0 + 8*j], w0, w1);
        }
    }
    __syncthreads();

    // GEMM2
    f32x4 acc2[2][8];
    #pragma unroll
    for (int m = 0; m < 2; ++m)
        #pragma unroll
        for (int n = 0; n < 8; ++n) acc2[m][n] = (f32x4){0.f, 0.f, 0.f, 0.f};

    #pragma unroll
    for (int kk = 0; kk < 4; ++kk) {
        const int k0 = kk * 32 + lhi * 8;
        bf16x8 a0 = *reinterpret_cast<const bf16x8*>(&h_lds[r0 + llo][k0]);
        bf16x8 a1 = *reinterpret_cast<const bf16x8*>(&h_lds[r0 + 16 + llo][k0]);
        #pragma unroll
        for (int nf = 0; nf < 8; ++nf) {
            bf16x8 b = *reinterpret_cast<const bf16x8*>(&w_lds[nf*16 + llo][k0]);
            acc2[0][nf] = __builtin_amdgcn_mfma_f32_16x16x32_bf16(a0, b, acc2[0][nf], 0, 0, 0);
            acc2[1][nf] = __builtin_amdgcn_mfma_f32_16x16x32_bf16(a1, b, acc2[1][nf], 0, 0, 0);
        }
    }

    // LayerNorm per row (128 cols live in the 16 llo-lanes x 8 nf frags), + residual + relu
    #pragma unroll
    for (int mf = 0; mf < 2; ++mf) {
        #pragma unroll
        for (int r = 0; r < 4; ++r) {
            float hv[8];
            float ssum = 0.f;
            #pragma unroll
            for (int nf = 0; nf < 8; ++nf) {
                const float v = acc2[mf][nf][r] + b2v[nf];
                hv[nf] = v; ssum += v;
            }
            ssum += __shfl_xor(ssum, 1); ssum += __shfl_xor(ssum, 2);
            ssum += __shfl_xor(ssum, 4); ssum += __shfl_xor(ssum, 8);
            const float mu = ssum * (1.0f/128.0f);
            float qs = 0.f;
            #pragma unroll
            for (int nf = 0; nf < 8; ++nf) { const float dd = hv[nf] - mu; qs += dd*dd; }
            qs += __shfl_xor(qs, 1); qs += __shfl_xor(qs, 2);
            qs += __shfl_xor(qs, 4); qs += __shfl_xor(qs, 8);
            const float rstd = rsqrtf(qs * (1.0f/128.0f) + 1e-5f);

            const int nrow = n0 + r0 + mf*16 + lhi*4 + r;
            if (nrow < N) {
                const float* xr   = x   + (size_t)nrow * D;
                float*       orow = out + (size_t)nrow * D;
                #pragma unroll
                for (int nf = 0; nf < 8; ++nf) {
                    const int col = nf*16 + llo;
                    const float v = (hv[nf] - mu) * rstd * lgv[nf] + lbv[nf] + xr[col];
                    orow[col] = fmaxf(v, 0.0f);
                }
            }
        }
    }
}

extern "C" void kernel_launch(void* const* d_in, const int* in_sizes, int n_in,
                              void* d_out, int out_size, void* d_ws, size_t ws_size,
                              hipStream_t stream) {
    const float* x     = (const float*)d_in[0];
    const int*   ei    = (const int*)d_in[1];    // int32 per harness convention
    const float* ea    = (const float*)d_in[2];
    const float* epsp  = (const float*)d_in[3];
    const float* We    = (const float*)d_in[4];
    const float* be    = (const float*)d_in[5];
    const float* W1    = (const float*)d_in[6];
    const float* b1    = (const float*)d_in[7];
    const float* bn_g  = (const float*)d_in[8];
    const float* bn_b  = (const float*)d_in[9];
    const float* bn_rm = (const float*)d_in[10];
    const float* bn_rv = (const float*)d_in[11];
    const float* W2    = (const float*)d_in[12];
    const float* b2    = (const float*)d_in[13];
    const float* ln_g  = (const float*)d_in[14];
    const float* ln_b  = (const float*)d_in[15];
    float* out = (float*)d_out;

    const int N = in_sizes[0] / D;     // 50000
    const int E = in_sizes[2] / D;     // 800000
    const size_t aggr_bytes = (size_t)N * D * sizeof(float);

    // aggregation scratch: d_ws if it fits, else d_out (node block touches only its own rows)
    float* aggr = (ws_size >= aggr_bytes) ? (float*)d_ws : out;

    hipMemsetAsync(aggr, 0, aggr_bytes, stream);

    const int eblocks = (E + 127) / 128;
    gine_edge<<<eblocks, 256, 0, stream>>>(x, ei, ea, We, be, aggr, E);

    const int nblocks = (N + 127) / 128;
    gine_node<<<nblocks, 256, 0, stream>>>(x, aggr, epsp, W1, b1, bn_g, bn_b,
                                           bn_rm, bn_rv, W2, b2, ln_g, ln_b, out, N);
}

// Round 4
// 473.360 us; speedup vs baseline: 1.1695x; 1.1695x over previous
//
#include <hip/hip_runtime.h>
#include <hip/hip_bf16.h>

#define D 128
#define LDK 136  // padded LDS row: 136 bf16 = 272B

typedef __bf16 bf16x8 __attribute__((ext_vector_type(8)));
typedef float  f32x4  __attribute__((ext_vector_type(4)));
typedef unsigned short u16;

// fp32 -> bf16 round-to-nearest-even
__device__ __forceinline__ u16 f2bf(float f) {
    unsigned int u = __builtin_bit_cast(unsigned int, f);
    u = u + 0x7FFFu + ((u >> 16) & 1u);
    return (u16)(u >> 16);
}
__device__ __forceinline__ unsigned int pk2(float lo, float hi) {
    return (unsigned int)f2bf(lo) | ((unsigned int)f2bf(hi) << 16);
}
// convert 8 fp32 -> 8 bf16, one 16B LDS store (dst 16B aligned)
__device__ __forceinline__ void cvt_store8(u16* dst, float4 a, float4 b) {
    uint4 v;
    v.x = pk2(a.x, a.y); v.y = pk2(a.z, a.w);
    v.z = pk2(b.x, b.y); v.w = pk2(b.z, b.w);
    *reinterpret_cast<uint4*>(dst) = v;
}
// convert 8 fp32 (two native ext-vectors) -> bf16x8 fragment in registers
__device__ __forceinline__ bf16x8 cvt8r(f32x4 a, f32x4 b) {
    uint4 v;
    v.x = pk2(a.x, a.y); v.y = pk2(a.z, a.w);
    v.z = pk2(b.x, b.y); v.w = pk2(b.z, b.w);
    return __builtin_bit_cast(bf16x8, v);
}

// ---------------- edge kernel: msg = relu(x[src] + ea@We^T + be); atomic scatter to aggr[dst]
// A-fragments (edge_attr) are loaded NON-TEMPORAL straight to registers: no a_lds
// (halves LDS -> 4 blocks/CU) and no L2 allocation (keeps aggr resident in L2 so
// the scatter atomics hit in L2 instead of thrash-writeback to HBM).
__global__ __launch_bounds__(256, 4)
void gine_edge(const float* __restrict__ x,
               const int* __restrict__ ei,      // int32 (harness converts integer inputs)
               const float* __restrict__ ea,
               const float* __restrict__ We,
               const float* __restrict__ be,
               float* __restrict__ aggr,
               int E)
{
    __shared__ u16 w_lds[128][LDK];   // We[o][k] (bf16)
    __shared__ int sd_lds[2][128];    // src, dst

    const int tid = threadIdx.x;
    const int e0  = blockIdx.x * 128;

    {   // stage We: thread t -> row t>>1, 64-col half (t&1)
        const int row = tid >> 1;
        const int c0  = (tid & 1) * 64;
        const float4* gw = reinterpret_cast<const float4*>(We + (size_t)row * D + c0);
        #pragma unroll
        for (int j = 0; j < 8; ++j) {
            float4 w0 = gw[2*j], w1 = gw[2*j+1];
            cvt_store8(&w_lds[row][c0 + 8*j], w0, w1);
        }
        // stage src/dst
        const int r = tid & 127, which = tid >> 7;
        int erow = e0 + r;
        sd_lds[which][r] = (erow < E) ? ei[(size_t)which * E + erow] : 0;
    }
    __syncthreads();

    const int wave = tid >> 6, lane = tid & 63;
    const int lhi = lane >> 4, llo = lane & 15;
    const int r0 = wave * 32;   // wave owns 32 tile rows x 128 cols

    f32x4 acc[2][8];
    #pragma unroll
    for (int m = 0; m < 2; ++m)
        #pragma unroll
        for (int n = 0; n < 8; ++n) acc[m][n] = (f32x4){0.f, 0.f, 0.f, 0.f};

    // A rows this lane feeds (clamped; harmless dup work on ragged tail)
    int ra = e0 + r0 + llo;      if (ra >= E) ra = E - 1;
    int rb = e0 + r0 + 16 + llo; if (rb >= E) rb = E - 1;
    const f32x4* pa = reinterpret_cast<const f32x4*>(ea + (size_t)ra * D);
    const f32x4* pb = reinterpret_cast<const f32x4*>(ea + (size_t)rb * D);

    #pragma unroll
    for (int kk = 0; kk < 4; ++kk) {
        const int k0 = kk * 32 + lhi * 8;
        const int f4 = k0 >> 2;
        f32x4 u0 = __builtin_nontemporal_load(pa + f4);
        f32x4 u1 = __builtin_nontemporal_load(pa + f4 + 1);
        f32x4 v0 = __builtin_nontemporal_load(pb + f4);
        f32x4 v1 = __builtin_nontemporal_load(pb + f4 + 1);
        bf16x8 a0 = cvt8r(u0, u1);
        bf16x8 a1 = cvt8r(v0, v1);
        #pragma unroll
        for (int nf = 0; nf < 8; ++nf) {
            bf16x8 b = *reinterpret_cast<const bf16x8*>(&w_lds[nf*16 + llo][k0]);
            acc[0][nf] = __builtin_amdgcn_mfma_f32_16x16x32_bf16(a0, b, acc[0][nf], 0, 0, 0);
            acc[1][nf] = __builtin_amdgcn_mfma_f32_16x16x32_bf16(a1, b, acc[1][nf], 0, 0, 0);
        }
    }

    float bev[8];
    #pragma unroll
    for (int nf = 0; nf < 8; ++nf) bev[nf] = be[nf*16 + llo];

    // epilogue: C/D frag (col = lane&15, row = (lane>>4)*4 + reg)
    #pragma unroll
    for (int mf = 0; mf < 2; ++mf) {
        #pragma unroll
        for (int r = 0; r < 4; ++r) {
            const int row = r0 + mf*16 + lhi*4 + r;
            if (e0 + row >= E) continue;
            const int s = sd_lds[0][row];
            const int d = sd_lds[1][row];
            const float* xr  = x    + (size_t)s * D;
            float*      arow = aggr + (size_t)d * D;
            #pragma unroll
            for (int nf = 0; nf < 8; ++nf) {
                const int col = nf*16 + llo;
                float v = acc[mf][nf][r] + xr[col] + bev[nf];
                v = fmaxf(v, 0.0f);
                atomicAdd(&arow[col], v);
            }
        }
    }
}

// ---------------- node kernel: h0=(1+eps)x+aggr; GEMM1+BN+ReLU; GEMM2+b2; LN; relu(+x)
__global__ __launch_bounds__(256, 2)
void gine_node(const float* __restrict__ x,
               const float* __restrict__ aggr,
               const float* __restrict__ epsp,
               const float* __restrict__ W1,
               const float* __restrict__ b1,
               const float* __restrict__ bn_g,
               const float* __restrict__ bn_b,
               const float* __restrict__ bn_rm,
               const float* __restrict__ bn_rv,
               const float* __restrict__ W2,
               const float* __restrict__ b2,
               const float* __restrict__ ln_g,
               const float* __restrict__ ln_b,
               float* __restrict__ out,
               int N)
{
    __shared__ u16 h_lds[128][LDK];   // A operand: h0 then h1
    __shared__ u16 w_lds[128][LDK];   // B operand: W1 then W2

    const int tid = threadIdx.x;
    const int n0  = blockIdx.x * 128;
    const float epf = 1.0f + epsp[0];

    {   // stage h0 = (1+eps)*x + aggr, and W1
        const int row = tid >> 1;
        const int c0  = (tid & 1) * 64;
        int nrow = n0 + row; if (nrow >= N) nrow = N - 1;
        const float4* gx = reinterpret_cast<const float4*>(x    + (size_t)nrow * D + c0);
        const float4* ga = reinterpret_cast<const float4*>(aggr + (size_t)nrow * D + c0);
        const float4* gw = reinterpret_cast<const float4*>(W1   + (size_t)row  * D + c0);
        #pragma unroll
        for (int j = 0; j < 8; ++j) {
            float4 xv0 = gx[2*j], xv1 = gx[2*j+1];
            float4 av0 = ga[2*j], av1 = ga[2*j+1];
            float4 h0, h1;
            h0.x = epf*xv0.x + av0.x; h0.y = epf*xv0.y + av0.y;
            h0.z = epf*xv0.z + av0.z; h0.w = epf*xv0.w + av0.w;
            h1.x = epf*xv1.x + av1.x; h1.y = epf*xv1.y + av1.y;
            h1.z = epf*xv1.z + av1.z; h1.w = epf*xv1.w + av1.w;
            cvt_store8(&h_lds[row][c0 + 8*j], h0, h1);
            float4 w0 = gw[2*j], w1 = gw[2*j+1];
            cvt_store8(&w_lds[row][c0 + 8*j], w0, w1);
        }
    }
    __syncthreads();

    const int wave = tid >> 6, lane = tid & 63;
    const int lhi = lane >> 4, llo = lane & 15;
    const int r0 = wave * 32;

    f32x4 acc[2][8];
    #pragma unroll
    for (int m = 0; m < 2; ++m)
        #pragma unroll
        for (int n = 0; n < 8; ++n) acc[m][n] = (f32x4){0.f, 0.f, 0.f, 0.f};

    #pragma unroll
    for (int kk = 0; kk < 4; ++kk) {
        const int k0 = kk * 32 + lhi * 8;
        bf16x8 a0 = *reinterpret_cast<const bf16x8*>(&h_lds[r0 + llo][k0]);
        bf16x8 a1 = *reinterpret_cast<const bf16x8*>(&h_lds[r0 + 16 + llo][k0]);
        #pragma unroll
        for (int nf = 0; nf < 8; ++nf) {
            bf16x8 b = *reinterpret_cast<const bf16x8*>(&w_lds[nf*16 + llo][k0]);
            acc[0][nf] = __builtin_amdgcn_mfma_f32_16x16x32_bf16(a0, b, acc[0][nf], 0, 0, 0);
            acc[1][nf] = __builtin_amdgcn_mfma_f32_16x16x32_bf16(a1, b, acc[1][nf], 0, 0, 0);
        }
    }

    // per-lane per-column constants (col = nf*16 + llo)
    float sc[8], bi[8], b2v[8], lgv[8], lbv[8];
    #pragma unroll
    for (int nf = 0; nf < 8; ++nf) {
        const int c = nf*16 + llo;
        const float s = bn_g[c] * rsqrtf(bn_rv[c] + 1e-5f);
        sc[nf]  = s;
        bi[nf]  = (b1[c] - bn_rm[c]) * s + bn_b[c];   // BN folded with b1
        b2v[nf] = b2[c];
        lgv[nf] = ln_g[c];
        lbv[nf] = ln_b[c];
    }

    __syncthreads();   // all GEMM1 LDS reads complete before overwrite

    // h1 = relu(BN(GEMM1)) -> h_lds (bf16, scattered u16 stores); stage W2
    #pragma unroll
    for (int mf = 0; mf < 2; ++mf) {
        #pragma unroll
        for (int r = 0; r < 4; ++r) {
            const int row = r0 + mf*16 + lhi*4 + r;
            #pragma unroll
            for (int nf = 0; nf < 8; ++nf) {
                const int col = nf*16 + llo;
                const float v = fmaxf(acc[mf][nf][r] * sc[nf] + bi[nf], 0.0f);
                h_lds[row][col] = f2bf(v);
            }
        }
    }
    {
        const int row = tid >> 1;
        const int c0  = (tid & 1) * 64;
        const float4* gw = reinterpret_cast<const float4*>(W2 + (size_t)row * D + c0);
        #pragma unroll
        for (int j = 0; j < 8; ++j) {
            float4 w0 = gw[2*j], w1 = gw[2*j+1];
            cvt_store8(&w_lds[row][c0 + 8*j], w0, w1);
        }
    }
    __syncthreads();

    // GEMM2
    f32x4 acc2[2][8];
    #pragma unroll
    for (int m = 0; m < 2; ++m)
        #pragma unroll
        for (int n = 0; n < 8; ++n) acc2[m][n] = (f32x4){0.f, 0.f, 0.f, 0.f};

    #pragma unroll
    for (int kk = 0; kk < 4; ++kk) {
        const int k0 = kk * 32 + lhi * 8;
        bf16x8 a0 = *reinterpret_cast<const bf16x8*>(&h_lds[r0 + llo][k0]);
        bf16x8 a1 = *reinterpret_cast<const bf16x8*>(&h_lds[r0 + 16 + llo][k0]);
        #pragma unroll
        for (int nf = 0; nf < 8; ++nf) {
            bf16x8 b = *reinterpret_cast<const bf16x8*>(&w_lds[nf*16 + llo][k0]);
            acc2[0][nf] = __builtin_amdgcn_mfma_f32_16x16x32_bf16(a0, b, acc2[0][nf], 0, 0, 0);
            acc2[1][nf] = __builtin_amdgcn_mfma_f32_16x16x32_bf16(a1, b, acc2[1][nf], 0, 0, 0);
        }
    }

    // LayerNorm per row (128 cols live in the 16 llo-lanes x 8 nf frags), + residual + relu
    #pragma unroll
    for (int mf = 0; mf < 2; ++mf) {
        #pragma unroll
        for (int r = 0; r < 4; ++r) {
            float hv[8];
            float ssum = 0.f;
            #pragma unroll
            for (int nf = 0; nf < 8; ++nf) {
                const float v = acc2[mf][nf][r] + b2v[nf];
                hv[nf] = v; ssum += v;
            }
            ssum += __shfl_xor(ssum, 1); ssum += __shfl_xor(ssum, 2);
            ssum += __shfl_xor(ssum, 4); ssum += __shfl_xor(ssum, 8);
            const float mu = ssum * (1.0f/128.0f);
            float qs = 0.f;
            #pragma unroll
            for (int nf = 0; nf < 8; ++nf) { const float dd = hv[nf] - mu; qs += dd*dd; }
            qs += __shfl_xor(qs, 1); qs += __shfl_xor(qs, 2);
            qs += __shfl_xor(qs, 4); qs += __shfl_xor(qs, 8);
            const float rstd = rsqrtf(qs * (1.0f/128.0f) + 1e-5f);

            const int nrow = n0 + r0 + mf*16 + lhi*4 + r;
            if (nrow < N) {
                const float* xr   = x   + (size_t)nrow * D;
                float*       orow = out + (size_t)nrow * D;
                #pragma unroll
                for (int nf = 0; nf < 8; ++nf) {
                    const int col = nf*16 + llo;
                    const float v = (hv[nf] - mu) * rstd * lgv[nf] + lbv[nf] + xr[col];
                    orow[col] = fmaxf(v, 0.0f);
                }
            }
        }
    }
}

extern "C" void kernel_launch(void* const* d_in, const int* in_sizes, int n_in,
                              void* d_out, int out_size, void* d_ws, size_t ws_size,
                              hipStream_t stream) {
    const float* x     = (const float*)d_in[0];
    const int*   ei    = (const int*)d_in[1];    // int32 per harness convention
    const float* ea    = (const float*)d_in[2];
    const float* epsp  = (const float*)d_in[3];
    const float* We    = (const float*)d_in[4];
    const float* be    = (const float*)d_in[5];
    const float* W1    = (const float*)d_in[6];
    const float* b1    = (const float*)d_in[7];
    const float* bn_g  = (const float*)d_in[8];
    const float* bn_b  = (const float*)d_in[9];
    const float* bn_rm = (const float*)d_in[10];
    const float* bn_rv = (const float*)d_in[11];
    const float* W2    = (const float*)d_in[12];
    const float* b2    = (const float*)d_in[13];
    const float* ln_g  = (const float*)d_in[14];
    const float* ln_b  = (const float*)d_in[15];
    float* out = (float*)d_out;

    const int N = in_sizes[0] / D;     // 50000
    const int E = in_sizes[2] / D;     // 800000
    const size_t aggr_bytes = (size_t)N * D * sizeof(float);

    // aggregation scratch: d_ws if it fits, else d_out (node block touches only its own rows)
    float* aggr = (ws_size >= aggr_bytes) ? (float*)d_ws : out;

    (void)hipMemsetAsync(aggr, 0, aggr_bytes, stream);

    const int eblocks = (E + 127) / 128;
    gine_edge<<<eblocks, 256, 0, stream>>>(x, ei, ea, We, be, aggr, E);

    const int nblocks = (N + 127) / 128;
    gine_node<<<nblocks, 256, 0, stream>>>(x, aggr, epsp, W1, b1, bn_g, bn_b,
                                           bn_rm, bn_rv, W2, b2, ln_g, ln_b, out, N);
}